// Round 4
// baseline (797.632 us; speedup 1.0000x reference)
//
#include <hip/hip_runtime.h>
#include <stdint.h>

#define NN 100000
#define EE 1600000
#define FEAT 32
#define HID 64
#define MSG 32
#define GOALD 16
#define OUTD 8
#define UPD_IN 112
#define EPS 1e-5f

typedef float f32x2 __attribute__((ext_vector_type(2)));

// ---------- K1: column stats of x1 = relu(nodes@W_in + b_in) (x1 not stored) ----------
__global__ __launch_bounds__(256) void k_in_stats(
    const float* __restrict__ nodes, const float* __restrict__ W_in,
    const float* __restrict__ b_in, float* __restrict__ stats1)
{
    __shared__ float red[256];
    const int tid = threadIdx.x;
    const int j = tid & 63, slot = tid >> 6;
    float w[FEAT];
#pragma unroll
    for (int k = 0; k < FEAT; ++k) w[k] = W_in[k * HID + j];
    const float bj = b_in[j];
    float lsum = 0.f, lsq = 0.f;
    for (int i = blockIdx.x * 4 + slot; i < NN; i += gridDim.x * 4) {
        const float4* row = (const float4*)(nodes + (size_t)i * FEAT);
        float acc = bj;
#pragma unroll
        for (int q = 0; q < FEAT / 4; ++q) {
            float4 r = row[q];
            acc = fmaf(r.x, w[q * 4 + 0], acc);
            acc = fmaf(r.y, w[q * 4 + 1], acc);
            acc = fmaf(r.z, w[q * 4 + 2], acc);
            acc = fmaf(r.w, w[q * 4 + 3], acc);
        }
        float v = fmaxf(acc, 0.f);
        lsum += v; lsq += v * v;
    }
    red[tid] = lsum; __syncthreads();
    if (tid < 64) atomicAdd(&stats1[tid], red[tid] + red[tid + 64] + red[tid + 128] + red[tid + 192]);
    __syncthreads();
    red[tid] = lsq; __syncthreads();
    if (tid < 64) atomicAdd(&stats1[64 + tid], red[tid] + red[tid + 64] + red[tid + 128] + red[tid + 192]);
}

// ---------- K2: h = BN1(relu(nodes@W_in+b)) stored; x2 = relu(h@W_msg+b) stored; stats2 ----------
__global__ __launch_bounds__(256) void k_h_msg(
    const float* __restrict__ nodes, const float* __restrict__ W_in,
    const float* __restrict__ b_in, const float* __restrict__ stats1,
    const float* __restrict__ g_in, const float* __restrict__ be_in,
    const float* __restrict__ W_msg, const float* __restrict__ b_msg,
    float* __restrict__ h_out, float* __restrict__ x2_out,
    float* __restrict__ stats2)
{
    __shared__ float shh[4][HID];
    __shared__ float red[256];
    const int tid = threadIdx.x;
    const int j = tid & 63, slot = tid >> 6;
    const int j2 = j & 31, half = j >> 5;
    float w[FEAT];
#pragma unroll
    for (int k = 0; k < FEAT; ++k) w[k] = W_in[k * HID + j];
    float wm[32];
#pragma unroll
    for (int k = 0; k < 32; ++k) wm[k] = W_msg[(half * 32 + k) * MSG + j2];
    const float bj = b_in[j];
    const float m1 = stats1[j] * (1.f / NN);
    const float va1 = stats1[HID + j] * (1.f / NN) - m1 * m1;
    const float s1 = g_in[j] * rsqrtf(va1 + EPS);
    const float t1 = be_in[j] - m1 * s1;
    const float bm = b_msg[j2];
    float lsum = 0.f, lsq = 0.f;
    for (int base = blockIdx.x * 4; base < NN; base += gridDim.x * 4) {
        const int i = base + slot;
        const bool act = i < NN;
        float hv = 0.f;
        if (act) {
            const float4* row = (const float4*)(nodes + (size_t)i * FEAT);
            float acc = bj;
#pragma unroll
            for (int q = 0; q < FEAT / 4; ++q) {
                float4 r = row[q];
                acc = fmaf(r.x, w[q * 4 + 0], acc);
                acc = fmaf(r.y, w[q * 4 + 1], acc);
                acc = fmaf(r.z, w[q * 4 + 2], acc);
                acc = fmaf(r.w, w[q * 4 + 3], acc);
            }
            hv = fmaf(fmaxf(acc, 0.f), s1, t1);
            h_out[(size_t)i * HID + j] = hv;
        }
        shh[slot][j] = hv;
        __syncthreads();
        if (act) {
            const float4* hr = (const float4*)(&shh[slot][half * 32]);
            float acc2 = 0.f;
#pragma unroll
            for (int q = 0; q < 8; ++q) {
                float4 r = hr[q];
                acc2 = fmaf(r.x, wm[q * 4 + 0], acc2);
                acc2 = fmaf(r.y, wm[q * 4 + 1], acc2);
                acc2 = fmaf(r.z, wm[q * 4 + 2], acc2);
                acc2 = fmaf(r.w, wm[q * 4 + 3], acc2);
            }
            acc2 += __shfl_xor(acc2, 32);
            if (half == 0) {
                float v = fmaxf(acc2 + bm, 0.f);
                x2_out[(size_t)i * MSG + j2] = v;
                lsum += v; lsq += v * v;
            }
        }
        __syncthreads();
    }
    red[tid] = (half == 0) ? lsum : 0.f; __syncthreads();
    if (tid < 32) atomicAdd(&stats2[tid], red[tid] + red[tid + 64] + red[tid + 128] + red[tid + 192]);
    __syncthreads();
    red[tid] = (half == 0) ? lsq : 0.f; __syncthreads();
    if (tid < 32) atomicAdd(&stats2[32 + tid], red[tid] + red[tid + 64] + red[tid + 128] + red[tid + 192]);
}

// ---------- CSR build: histogram of dst ----------
__global__ __launch_bounds__(256) void k_hist(
    const int* __restrict__ edst, int* __restrict__ counts)
{
    const int stride = gridDim.x * blockDim.x;
    for (int e = blockIdx.x * blockDim.x + threadIdx.x; e < EE; e += stride)
        atomicAdd(&counts[edst[e]], 1);
}

// ---------- CSR build: single-block exclusive scan of counts -> offsets, cursor ----------
__global__ __launch_bounds__(1024) void k_scan(
    const int* __restrict__ counts, int* __restrict__ offsets, int* __restrict__ cursor)
{
    __shared__ int part[1024];
    const int tid = threadIdx.x;
    const int CH = (NN + 1023) / 1024;  // 98
    const int base = tid * CH;
    const int n = (base >= NN) ? 0 : ((NN - base < CH) ? (NN - base) : CH);
    int s = 0;
    for (int k = 0; k < n; ++k) s += counts[base + k];
    part[tid] = s;
    __syncthreads();
    for (int off = 1; off < 1024; off <<= 1) {
        int v = (tid >= off) ? part[tid - off] : 0;
        __syncthreads();
        part[tid] += v;
        __syncthreads();
    }
    int run = (tid == 0) ? 0 : part[tid - 1];
    for (int k = 0; k < n; ++k) {
        int c = counts[base + k];
        offsets[base + k] = run;
        cursor[base + k] = run;
        run += c;
    }
    if (tid == 1023) offsets[NN] = part[1023];
}

// ---------- CSR build: scatter src ids into dst buckets ----------
__global__ __launch_bounds__(256) void k_scatter(
    const int* __restrict__ esrc, const int* __restrict__ edst,
    int* __restrict__ cursor, int* __restrict__ perm)
{
    const int stride = gridDim.x * blockDim.x;
    for (int e = blockIdx.x * blockDim.x + threadIdx.x; e < EE; e += stride) {
        const int d = edst[e];
        const int pos = atomicAdd(&cursor[d], 1);
        perm[pos] = esrc[e];
    }
}

// ---------- K3: agg[i] = s2 * sum_{e in bucket(i)} x2[perm[e]] + deg*t2 ----------
// One wave per node; lane = channel (0..31) + edge-parity (bit 5). Output into
// the d_out u-region at stride 64 (cols 0..31); k_upd overwrites with x3 later.
__global__ __launch_bounds__(256) void k_agg(
    const int* __restrict__ offsets, const int* __restrict__ perm,
    const float* __restrict__ x2, const float* __restrict__ stats2,
    const float* __restrict__ g_msg, const float* __restrict__ be_msg,
    float* __restrict__ aggout)
{
    const int lane = threadIdx.x & 63;
    const int c = lane & 31, p = lane >> 5;
    const int wid = (blockIdx.x * blockDim.x + threadIdx.x) >> 6;
    const int nw = (gridDim.x * blockDim.x) >> 6;
    const float m = stats2[c] * (1.f / NN);
    const float va = stats2[MSG + c] * (1.f / NN) - m * m;
    const float s = g_msg[c] * rsqrtf(va + EPS);
    const float t = be_msg[c] - m * s;
    for (int i = wid; i < NN; i += nw) {
        const int beg = offsets[i], end = offsets[i + 1];
        float S = 0.f;
        for (int e = beg + p; e < end; e += 2) {
            const int si = perm[e];
            S += x2[(size_t)si * MSG + c];
        }
        S += __shfl_xor(S, 32);
        if (p == 0)
            aggout[(size_t)i * HID + c] = fmaf(s, S, (float)(end - beg) * t);
    }
}

// ---------- K4: x3 = relu([agg,h,goal]@W_upd + b); agg read from & x3 written to same buffer ----------
__global__ __launch_bounds__(256) void k_upd(
    float* __restrict__ aggx3, const float* __restrict__ h,
    const float* __restrict__ goal, const float* __restrict__ W_upd,
    const float* __restrict__ b_upd, float* __restrict__ stats3)
{
    __shared__ float cat[4][UPD_IN];
    __shared__ float red[256];
    const int tid = threadIdx.x;
    const int j = tid & 63, slot = tid >> 6;
    float w[UPD_IN];
#pragma unroll
    for (int k = 0; k < UPD_IN; ++k) w[k] = W_upd[k * HID + j];
    const float bj = b_upd[j];
    float lsum = 0.f, lsq = 0.f;
    for (int base = blockIdx.x * 4; base < NN; base += gridDim.x * 4) {
        const int i = base + slot;
        const bool act = i < NN;
        if (act) {
            if (j < 32) cat[slot][j] = aggx3[(size_t)i * HID + j];
            cat[slot][32 + j] = h[(size_t)i * HID + j];
            if (j < 16) cat[slot][96 + j] = goal[(size_t)i * GOALD + j];
        }
        __syncthreads();
        if (act) {
            const float4* cr = (const float4*)cat[slot];
            float acc = bj;
#pragma unroll
            for (int q = 0; q < UPD_IN / 4; ++q) {
                float4 r = cr[q];
                acc = fmaf(r.x, w[q * 4 + 0], acc);
                acc = fmaf(r.y, w[q * 4 + 1], acc);
                acc = fmaf(r.z, w[q * 4 + 2], acc);
                acc = fmaf(r.w, w[q * 4 + 3], acc);
            }
            float v = fmaxf(acc, 0.f);
            aggx3[(size_t)i * HID + j] = v;
            lsum += v; lsq += v * v;
        }
        __syncthreads();
    }
    red[tid] = lsum; __syncthreads();
    if (tid < 64) atomicAdd(&stats3[tid], red[tid] + red[tid + 64] + red[tid + 128] + red[tid + 192]);
    __syncthreads();
    red[tid] = lsq; __syncthreads();
    if (tid < 64) atomicAdd(&stats3[64 + tid], red[tid] + red[tid + 64] + red[tid + 128] + red[tid + 192]);
}

// ---------- K5: u = BN3(x3) in-place in d_out; out = u@W_out + b_out ----------
__global__ __launch_bounds__(256) void k_out(
    float* __restrict__ x3u, const float* __restrict__ stats3,
    const float* __restrict__ g_upd, const float* __restrict__ be_upd,
    const float* __restrict__ W_out, const float* __restrict__ b_out,
    float* __restrict__ o_out)
{
    __shared__ float shu[4][HID];
    const int tid = threadIdx.x;
    const int j = tid & 63, slot = tid >> 6;
    const int o = j & 7, part = j >> 3;
    const float m3 = stats3[j] * (1.f / NN);
    const float va3 = stats3[HID + j] * (1.f / NN) - m3 * m3;
    const float s3 = g_upd[j] * rsqrtf(va3 + EPS);
    const float t3 = be_upd[j] - m3 * s3;
    float w[8];
#pragma unroll
    for (int k = 0; k < 8; ++k) w[k] = W_out[(part * 8 + k) * OUTD + o];
    const float bo = b_out[o];
    for (int base = blockIdx.x * 4; base < NN; base += gridDim.x * 4) {
        const int i = base + slot;
        const bool act = i < NN;
        float u = 0.f;
        if (act) {
            u = fmaf(x3u[(size_t)i * HID + j], s3, t3);
            x3u[(size_t)i * HID + j] = u;
        }
        shu[slot][j] = u;
        __syncthreads();
        if (act) {
            const float* ur = &shu[slot][part * 8];
            float acc = 0.f;
#pragma unroll
            for (int k = 0; k < 8; ++k) acc = fmaf(ur[k], w[k], acc);
            acc += __shfl_xor(acc, 8);
            acc += __shfl_xor(acc, 16);
            acc += __shfl_xor(acc, 32);
            if (part == 0) o_out[(size_t)i * OUTD + o] = acc + bo;
        }
        __syncthreads();
    }
}

extern "C" void kernel_launch(void* const* d_in, const int* in_sizes, int n_in,
                              void* d_out, int out_size, void* d_ws, size_t ws_size,
                              hipStream_t stream)
{
    (void)in_sizes; (void)n_in; (void)out_size;
    const float* nodes  = (const float*)d_in[0];
    const float* goal   = (const float*)d_in[1];
    const int*   esrc   = (const int*)d_in[2];
    const int*   edst   = (const int*)d_in[3];
    const float* W_in   = (const float*)d_in[6];
    const float* b_in   = (const float*)d_in[7];
    const float* g_in   = (const float*)d_in[8];
    const float* be_in  = (const float*)d_in[9];
    const float* W_msg  = (const float*)d_in[10];
    const float* b_msg  = (const float*)d_in[11];
    const float* g_msg  = (const float*)d_in[12];
    const float* be_msg = (const float*)d_in[13];
    const float* W_upd  = (const float*)d_in[14];
    const float* b_upd  = (const float*)d_in[15];
    const float* g_upd  = (const float*)d_in[16];
    const float* be_upd = (const float*)d_in[17];
    const float* W_out  = (const float*)d_in[18];
    const float* b_out  = (const float*)d_in[19];

    // ws layout: stats(320 f32) | h(N*64 f32) | x2(N*32 f32) | counts(N) cursor(N) offsets(N+1) perm(E) int32
    const size_t need = (320 + (size_t)NN * 96) * sizeof(float)
                      + ((size_t)NN * 2 + 1 + EE) * sizeof(int);
    if (ws_size < need) return;  // fail soft instead of OOB-faulting

    float* st = (float*)d_ws;
    float* stats1 = st;        // 128
    float* stats2 = st + 128;  // 64
    float* stats3 = st + 192;  // 128
    float* h  = st + 320;                  // N*64
    float* x2 = h + (size_t)NN * 64;       // N*32
    int* counts  = (int*)(x2 + (size_t)NN * 32);
    int* cursor  = counts + NN;
    int* offsets = cursor + NN;            // N+1
    int* perm    = offsets + NN + 1;       // E

    float* u_out = (float*)d_out;                    // N*64 (agg cols 0..31 -> x3 -> u)
    float* o_out = (float*)d_out + (size_t)NN * HID; // N*8

    hipMemsetAsync(st, 0, 320 * sizeof(float), stream);
    hipMemsetAsync(counts, 0, NN * sizeof(int), stream);

    k_hist<<<2048, 256, 0, stream>>>(edst, counts);
    k_scan<<<1, 1024, 0, stream>>>(counts, offsets, cursor);
    k_scatter<<<2048, 256, 0, stream>>>(esrc, edst, cursor, perm);
    k_in_stats<<<1024, 256, 0, stream>>>(nodes, W_in, b_in, stats1);
    k_h_msg<<<1024, 256, 0, stream>>>(nodes, W_in, b_in, stats1, g_in, be_in,
                                      W_msg, b_msg, h, x2, stats2);
    k_agg<<<2048, 256, 0, stream>>>(offsets, perm, x2, stats2, g_msg, be_msg, u_out);
    k_upd<<<1024, 256, 0, stream>>>(u_out, h, goal, W_upd, b_upd, stats3);
    k_out<<<1024, 256, 0, stream>>>(u_out, stats3, g_upd, be_upd, W_out, b_out, o_out);
}

// Round 6
// 594.610 us; speedup vs baseline: 1.3414x; 1.3414x over previous
//
#include <hip/hip_runtime.h>
#include <stdint.h>

#define NN 100000
#define EE 1600000
#define FEAT 32
#define HID 64
#define MSG 32
#define GOALD 16
#define OUTD 8
#define UPD_IN 112
#define EPS 1e-5f
#define NB 391  // (NN+255)/256

// ---------- K1: column stats of x1 = relu(nodes@W_in + b_in) (x1 not stored) ----------
__global__ __launch_bounds__(256) void k_in_stats(
    const float* __restrict__ nodes, const float* __restrict__ W_in,
    const float* __restrict__ b_in, float* __restrict__ stats1)
{
    __shared__ float red[256];
    const int tid = threadIdx.x;
    const int j = tid & 63, slot = tid >> 6;
    float w[FEAT];
#pragma unroll
    for (int k = 0; k < FEAT; ++k) w[k] = W_in[k * HID + j];
    const float bj = b_in[j];
    float lsum = 0.f, lsq = 0.f;
    for (int i = blockIdx.x * 4 + slot; i < NN; i += gridDim.x * 4) {
        const float4* row = (const float4*)(nodes + (size_t)i * FEAT);
        float acc = bj;
#pragma unroll
        for (int q = 0; q < FEAT / 4; ++q) {
            float4 r = row[q];
            acc = fmaf(r.x, w[q * 4 + 0], acc);
            acc = fmaf(r.y, w[q * 4 + 1], acc);
            acc = fmaf(r.z, w[q * 4 + 2], acc);
            acc = fmaf(r.w, w[q * 4 + 3], acc);
        }
        float v = fmaxf(acc, 0.f);
        lsum += v; lsq += v * v;
    }
    red[tid] = lsum; __syncthreads();
    if (tid < 64) atomicAdd(&stats1[tid], red[tid] + red[tid + 64] + red[tid + 128] + red[tid + 192]);
    __syncthreads();
    red[tid] = lsq; __syncthreads();
    if (tid < 64) atomicAdd(&stats1[64 + tid], red[tid] + red[tid + 64] + red[tid + 128] + red[tid + 192]);
}

// ---------- K2: h = BN1(relu(nodes@W_in+b)) stored; x2 = relu(h@W_msg+b) stored; stats2 ----------
__global__ __launch_bounds__(256) void k_h_msg(
    const float* __restrict__ nodes, const float* __restrict__ W_in,
    const float* __restrict__ b_in, const float* __restrict__ stats1,
    const float* __restrict__ g_in, const float* __restrict__ be_in,
    const float* __restrict__ W_msg, const float* __restrict__ b_msg,
    float* __restrict__ h_out, float* __restrict__ x2_out,
    float* __restrict__ stats2)
{
    __shared__ float shh[4][HID];
    __shared__ float red[256];
    const int tid = threadIdx.x;
    const int j = tid & 63, slot = tid >> 6;
    const int j2 = j & 31, half = j >> 5;
    float w[FEAT];
#pragma unroll
    for (int k = 0; k < FEAT; ++k) w[k] = W_in[k * HID + j];
    float wm[32];
#pragma unroll
    for (int k = 0; k < 32; ++k) wm[k] = W_msg[(half * 32 + k) * MSG + j2];
    const float bj = b_in[j];
    const float m1 = stats1[j] * (1.f / NN);
    const float va1 = stats1[HID + j] * (1.f / NN) - m1 * m1;
    const float s1 = g_in[j] * rsqrtf(va1 + EPS);
    const float t1 = be_in[j] - m1 * s1;
    const float bm = b_msg[j2];
    float lsum = 0.f, lsq = 0.f;
    for (int base = blockIdx.x * 4; base < NN; base += gridDim.x * 4) {
        const int i = base + slot;
        const bool act = i < NN;
        float hv = 0.f;
        if (act) {
            const float4* row = (const float4*)(nodes + (size_t)i * FEAT);
            float acc = bj;
#pragma unroll
            for (int q = 0; q < FEAT / 4; ++q) {
                float4 r = row[q];
                acc = fmaf(r.x, w[q * 4 + 0], acc);
                acc = fmaf(r.y, w[q * 4 + 1], acc);
                acc = fmaf(r.z, w[q * 4 + 2], acc);
                acc = fmaf(r.w, w[q * 4 + 3], acc);
            }
            hv = fmaf(fmaxf(acc, 0.f), s1, t1);
            h_out[(size_t)i * HID + j] = hv;
        }
        shh[slot][j] = hv;
        __syncthreads();
        if (act) {
            const float4* hr = (const float4*)(&shh[slot][half * 32]);
            float acc2 = 0.f;
#pragma unroll
            for (int q = 0; q < 8; ++q) {
                float4 r = hr[q];
                acc2 = fmaf(r.x, wm[q * 4 + 0], acc2);
                acc2 = fmaf(r.y, wm[q * 4 + 1], acc2);
                acc2 = fmaf(r.z, wm[q * 4 + 2], acc2);
                acc2 = fmaf(r.w, wm[q * 4 + 3], acc2);
            }
            acc2 += __shfl_xor(acc2, 32);
            if (half == 0) {
                float v = fmaxf(acc2 + bm, 0.f);
                x2_out[(size_t)i * MSG + j2] = v;
                lsum += v; lsq += v * v;
            }
        }
        __syncthreads();
    }
    red[tid] = (half == 0) ? lsum : 0.f; __syncthreads();
    if (tid < 32) atomicAdd(&stats2[tid], red[tid] + red[tid + 64] + red[tid + 128] + red[tid + 192]);
    __syncthreads();
    red[tid] = (half == 0) ? lsq : 0.f; __syncthreads();
    if (tid < 32) atomicAdd(&stats2[32 + tid], red[tid] + red[tid + 64] + red[tid + 128] + red[tid + 192]);
}

// ---------- CSR build: histogram of dst ----------
__global__ __launch_bounds__(256) void k_hist(
    const int* __restrict__ edst, int* __restrict__ counts)
{
    const int stride = gridDim.x * blockDim.x;
    for (int e = blockIdx.x * blockDim.x + threadIdx.x; e < EE; e += stride)
        atomicAdd(&counts[edst[e]], 1);
}

// ---------- scan phase A: per-block reduce of 256 counts ----------
__global__ __launch_bounds__(256) void k_scan_a(
    const int* __restrict__ counts, int* __restrict__ bsum)
{
    __shared__ int red[256];
    const int t = threadIdx.x;
    const int i = blockIdx.x * 256 + t;
    red[t] = (i < NN) ? counts[i] : 0;
    __syncthreads();
#pragma unroll
    for (int off = 128; off > 0; off >>= 1) {
        if (t < off) red[t] += red[t + off];
        __syncthreads();
    }
    if (t == 0) bsum[blockIdx.x] = red[0];
}

// ---------- scan phase B: exclusive scan of NB block sums (1 block) ----------
__global__ __launch_bounds__(512) void k_scan_b(
    const int* __restrict__ bsum, int* __restrict__ bpre)
{
    __shared__ int s[512];
    const int t = threadIdx.x;
    const int v = (t < NB) ? bsum[t] : 0;
    s[t] = v;
    __syncthreads();
#pragma unroll
    for (int off = 1; off < 512; off <<= 1) {
        const int u = (t >= off) ? s[t - off] : 0;
        __syncthreads();
        s[t] += u;
        __syncthreads();
    }
    if (t < NB) bpre[t] = s[t] - v;  // exclusive prefix
}

// ---------- scan phase C: block-local scan + block prefix -> offsets, cursor ----------
__global__ __launch_bounds__(256) void k_scan_c(
    const int* __restrict__ counts, const int* __restrict__ bpre,
    int* __restrict__ offsets, int* __restrict__ cursor)
{
    __shared__ int s[256];
    const int t = threadIdx.x;
    const int i = blockIdx.x * 256 + t;
    const int v = (i < NN) ? counts[i] : 0;
    s[t] = v;
    __syncthreads();
#pragma unroll
    for (int off = 1; off < 256; off <<= 1) {
        const int u = (t >= off) ? s[t - off] : 0;
        __syncthreads();
        s[t] += u;
        __syncthreads();
    }
    if (i < NN) {
        const int pref = bpre[blockIdx.x] + s[t] - v;
        offsets[i] = pref;
        cursor[i] = pref;
        if (i == NN - 1) offsets[NN] = pref + v;
    }
}

// ---------- CSR build: scatter src ids into dst buckets ----------
__global__ __launch_bounds__(256) void k_scatter(
    const int* __restrict__ esrc, const int* __restrict__ edst,
    int* __restrict__ cursor, int* __restrict__ perm)
{
    const int stride = gridDim.x * blockDim.x;
    for (int e = blockIdx.x * blockDim.x + threadIdx.x; e < EE; e += stride) {
        const int d = edst[e];
        const int pos = atomicAdd(&cursor[d], 1);
        perm[pos] = esrc[e];
    }
}

// ---------- K3: agg[i] = s2 * sum_{e in bucket(i)} x2[perm[e]] + deg*t2 ----------
__global__ __launch_bounds__(256) void k_agg(
    const int* __restrict__ offsets, const int* __restrict__ perm,
    const float* __restrict__ x2, const float* __restrict__ stats2,
    const float* __restrict__ g_msg, const float* __restrict__ be_msg,
    float* __restrict__ aggout)
{
    const int lane = threadIdx.x & 63;
    const int c = lane & 31, p = lane >> 5;
    const int wid = (blockIdx.x * blockDim.x + threadIdx.x) >> 6;
    const int nw = (gridDim.x * blockDim.x) >> 6;
    const float m = stats2[c] * (1.f / NN);
    const float va = stats2[MSG + c] * (1.f / NN) - m * m;
    const float s = g_msg[c] * rsqrtf(va + EPS);
    const float t = be_msg[c] - m * s;
    for (int i = wid; i < NN; i += nw) {
        const int beg = offsets[i], end = offsets[i + 1];
        float S = 0.f;
        for (int e = beg + p; e < end; e += 2) {
            const int si = perm[e];
            S += x2[(size_t)si * MSG + c];
        }
        S += __shfl_xor(S, 32);
        if (p == 0)
            aggout[(size_t)i * HID + c] = fmaf(s, S, (float)(end - beg) * t);
    }
}

// ---------- K4: x3 = relu([agg,h,goal]@W_upd + b); in-place in d_out u-region ----------
__global__ __launch_bounds__(256) void k_upd(
    float* __restrict__ aggx3, const float* __restrict__ h,
    const float* __restrict__ goal, const float* __restrict__ W_upd,
    const float* __restrict__ b_upd, float* __restrict__ stats3)
{
    __shared__ float cat[4][UPD_IN];
    __shared__ float red[256];
    const int tid = threadIdx.x;
    const int j = tid & 63, slot = tid >> 6;
    float w[UPD_IN];
#pragma unroll
    for (int k = 0; k < UPD_IN; ++k) w[k] = W_upd[k * HID + j];
    const float bj = b_upd[j];
    float lsum = 0.f, lsq = 0.f;
    for (int base = blockIdx.x * 4; base < NN; base += gridDim.x * 4) {
        const int i = base + slot;
        const bool act = i < NN;
        if (act) {
            if (j < 32) cat[slot][j] = aggx3[(size_t)i * HID + j];
            cat[slot][32 + j] = h[(size_t)i * HID + j];
            if (j < 16) cat[slot][96 + j] = goal[(size_t)i * GOALD + j];
        }
        __syncthreads();
        if (act) {
            const float4* cr = (const float4*)cat[slot];
            float acc = bj;
#pragma unroll
            for (int q = 0; q < UPD_IN / 4; ++q) {
                float4 r = cr[q];
                acc = fmaf(r.x, w[q * 4 + 0], acc);
                acc = fmaf(r.y, w[q * 4 + 1], acc);
                acc = fmaf(r.z, w[q * 4 + 2], acc);
                acc = fmaf(r.w, w[q * 4 + 3], acc);
            }
            float v = fmaxf(acc, 0.f);
            aggx3[(size_t)i * HID + j] = v;
            lsum += v; lsq += v * v;
        }
        __syncthreads();
    }
    red[tid] = lsum; __syncthreads();
    if (tid < 64) atomicAdd(&stats3[tid], red[tid] + red[tid + 64] + red[tid + 128] + red[tid + 192]);
    __syncthreads();
    red[tid] = lsq; __syncthreads();
    if (tid < 64) atomicAdd(&stats3[64 + tid], red[tid] + red[tid + 64] + red[tid + 128] + red[tid + 192]);
}

// ---------- K5: u = BN3(x3) in-place in d_out; out = u@W_out + b_out ----------
__global__ __launch_bounds__(256) void k_out(
    float* __restrict__ x3u, const float* __restrict__ stats3,
    const float* __restrict__ g_upd, const float* __restrict__ be_upd,
    const float* __restrict__ W_out, const float* __restrict__ b_out,
    float* __restrict__ o_out)
{
    __shared__ float shu[4][HID];
    const int tid = threadIdx.x;
    const int j = tid & 63, slot = tid >> 6;
    const int o = j & 7, part = j >> 3;
    const float m3 = stats3[j] * (1.f / NN);
    const float va3 = stats3[HID + j] * (1.f / NN) - m3 * m3;
    const float s3 = g_upd[j] * rsqrtf(va3 + EPS);
    const float t3 = be_upd[j] - m3 * s3;
    float w[8];
#pragma unroll
    for (int k = 0; k < 8; ++k) w[k] = W_out[(part * 8 + k) * OUTD + o];
    const float bo = b_out[o];
    for (int base = blockIdx.x * 4; base < NN; base += gridDim.x * 4) {
        const int i = base + slot;
        const bool act = i < NN;
        float u = 0.f;
        if (act) {
            u = fmaf(x3u[(size_t)i * HID + j], s3, t3);
            x3u[(size_t)i * HID + j] = u;
        }
        shu[slot][j] = u;
        __syncthreads();
        if (act) {
            const float* ur = &shu[slot][part * 8];
            float acc = 0.f;
#pragma unroll
            for (int k = 0; k < 8; ++k) acc = fmaf(ur[k], w[k], acc);
            acc += __shfl_xor(acc, 8);
            acc += __shfl_xor(acc, 16);
            acc += __shfl_xor(acc, 32);
            if (part == 0) o_out[(size_t)i * OUTD + o] = acc + bo;
        }
        __syncthreads();
    }
}

extern "C" void kernel_launch(void* const* d_in, const int* in_sizes, int n_in,
                              void* d_out, int out_size, void* d_ws, size_t ws_size,
                              hipStream_t stream)
{
    (void)in_sizes; (void)n_in; (void)out_size;
    const float* nodes  = (const float*)d_in[0];
    const float* goal   = (const float*)d_in[1];
    const int*   esrc   = (const int*)d_in[2];
    const int*   edst   = (const int*)d_in[3];
    const float* W_in   = (const float*)d_in[6];
    const float* b_in   = (const float*)d_in[7];
    const float* g_in   = (const float*)d_in[8];
    const float* be_in  = (const float*)d_in[9];
    const float* W_msg  = (const float*)d_in[10];
    const float* b_msg  = (const float*)d_in[11];
    const float* g_msg  = (const float*)d_in[12];
    const float* be_msg = (const float*)d_in[13];
    const float* W_upd  = (const float*)d_in[14];
    const float* b_upd  = (const float*)d_in[15];
    const float* g_upd  = (const float*)d_in[16];
    const float* be_upd = (const float*)d_in[17];
    const float* W_out  = (const float*)d_in[18];
    const float* b_out  = (const float*)d_in[19];

    // ws: stats(320 f32) | h(N*64) | x2(N*32) | counts(N) cursor(N) offsets(N+1) bsum(NB) bpre(NB) perm(E)
    const size_t need = (320 + (size_t)NN * 96) * sizeof(float)
                      + ((size_t)NN * 2 + 1 + 2 * NB + EE) * sizeof(int);
    if (ws_size < need) return;  // fail soft instead of OOB-faulting

    float* st = (float*)d_ws;
    float* stats1 = st;        // 128
    float* stats2 = st + 128;  // 64
    float* stats3 = st + 192;  // 128
    float* h  = st + 320;                  // N*64
    float* x2 = h + (size_t)NN * 64;       // N*32
    int* counts  = (int*)(x2 + (size_t)NN * 32);
    int* cursor  = counts + NN;
    int* offsets = cursor + NN;            // N+1
    int* bsum    = offsets + NN + 1;       // NB
    int* bpre    = bsum + NB;              // NB
    int* perm    = bpre + NB;              // E

    float* u_out = (float*)d_out;                    // N*64 (agg cols 0..31 -> x3 -> u)
    float* o_out = (float*)d_out + (size_t)NN * HID; // N*8

    hipMemsetAsync(st, 0, 320 * sizeof(float), stream);
    hipMemsetAsync(counts, 0, NN * sizeof(int), stream);

    k_hist<<<2048, 256, 0, stream>>>(edst, counts);
    k_scan_a<<<NB, 256, 0, stream>>>(counts, bsum);
    k_scan_b<<<1, 512, 0, stream>>>(bsum, bpre);
    k_scan_c<<<NB, 256, 0, stream>>>(counts, bpre, offsets, cursor);
    k_scatter<<<2048, 256, 0, stream>>>(esrc, edst, cursor, perm);
    k_in_stats<<<1024, 256, 0, stream>>>(nodes, W_in, b_in, stats1);
    k_h_msg<<<1024, 256, 0, stream>>>(nodes, W_in, b_in, stats1, g_in, be_in,
                                      W_msg, b_msg, h, x2, stats2);
    k_agg<<<2048, 256, 0, stream>>>(offsets, perm, x2, stats2, g_msg, be_msg, u_out);
    k_upd<<<1024, 256, 0, stream>>>(u_out, h, goal, W_upd, b_upd, stats3);
    k_out<<<1024, 256, 0, stream>>>(u_out, stats3, g_upd, be_upd, W_out, b_out, o_out);
}

// Round 9
// 480.709 us; speedup vs baseline: 1.6593x; 1.2369x over previous
//
#include <hip/hip_runtime.h>
#include <stdint.h>

#define NN 100000
#define EE 1600000
#define FEAT 32
#define HID 64
#define MSG 32
#define GOALD 16
#define OUTD 8
#define UPD_IN 112
#define EPS 1e-5f

// ---------- K1: column stats of x1 = relu(nodes@W_in + b_in) (x1 not stored) ----------
__global__ __launch_bounds__(256) void k_in_stats(
    const float* __restrict__ nodes, const float* __restrict__ W_in,
    const float* __restrict__ b_in, float* __restrict__ stats1)
{
    __shared__ float red[256];
    const int tid = threadIdx.x;
    const int j = tid & 63, slot = tid >> 6;
    float w[FEAT];
#pragma unroll
    for (int k = 0; k < FEAT; ++k) w[k] = W_in[k * HID + j];
    const float bj = b_in[j];
    float lsum = 0.f, lsq = 0.f;
    for (int i = blockIdx.x * 4 + slot; i < NN; i += gridDim.x * 4) {
        const float4* row = (const float4*)(nodes + (size_t)i * FEAT);
        float acc = bj;
#pragma unroll
        for (int q = 0; q < FEAT / 4; ++q) {
            float4 r = row[q];
            acc = fmaf(r.x, w[q * 4 + 0], acc);
            acc = fmaf(r.y, w[q * 4 + 1], acc);
            acc = fmaf(r.z, w[q * 4 + 2], acc);
            acc = fmaf(r.w, w[q * 4 + 3], acc);
        }
        float v = fmaxf(acc, 0.f);
        lsum += v; lsq += v * v;
    }
    red[tid] = lsum; __syncthreads();
    if (tid < 64) atomicAdd(&stats1[tid], red[tid] + red[tid + 64] + red[tid + 128] + red[tid + 192]);
    __syncthreads();
    red[tid] = lsq; __syncthreads();
    if (tid < 64) atomicAdd(&stats1[64 + tid], red[tid] + red[tid + 64] + red[tid + 128] + red[tid + 192]);
}

// ---------- K2: h = BN1(relu(nodes@W_in+b)) stored; x2 = relu(h@W_msg+b) stored; stats2 ----------
__global__ __launch_bounds__(256) void k_h_msg(
    const float* __restrict__ nodes, const float* __restrict__ W_in,
    const float* __restrict__ b_in, const float* __restrict__ stats1,
    const float* __restrict__ g_in, const float* __restrict__ be_in,
    const float* __restrict__ W_msg, const float* __restrict__ b_msg,
    float* __restrict__ h_out, float* __restrict__ x2_out,
    float* __restrict__ stats2)
{
    __shared__ float shh[4][HID];
    __shared__ float red[256];
    const int tid = threadIdx.x;
    const int j = tid & 63, slot = tid >> 6;
    const int j2 = j & 31, half = j >> 5;
    float w[FEAT];
#pragma unroll
    for (int k = 0; k < FEAT; ++k) w[k] = W_in[k * HID + j];
    float wm[32];
#pragma unroll
    for (int k = 0; k < 32; ++k) wm[k] = W_msg[(half * 32 + k) * MSG + j2];
    const float bj = b_in[j];
    const float m1 = stats1[j] * (1.f / NN);
    const float va1 = stats1[HID + j] * (1.f / NN) - m1 * m1;
    const float s1 = g_in[j] * rsqrtf(va1 + EPS);
    const float t1 = be_in[j] - m1 * s1;
    const float bm = b_msg[j2];
    float lsum = 0.f, lsq = 0.f;
    for (int base = blockIdx.x * 4; base < NN; base += gridDim.x * 4) {
        const int i = base + slot;
        const bool act = i < NN;
        float hv = 0.f;
        if (act) {
            const float4* row = (const float4*)(nodes + (size_t)i * FEAT);
            float acc = bj;
#pragma unroll
            for (int q = 0; q < FEAT / 4; ++q) {
                float4 r = row[q];
                acc = fmaf(r.x, w[q * 4 + 0], acc);
                acc = fmaf(r.y, w[q * 4 + 1], acc);
                acc = fmaf(r.z, w[q * 4 + 2], acc);
                acc = fmaf(r.w, w[q * 4 + 3], acc);
            }
            hv = fmaf(fmaxf(acc, 0.f), s1, t1);
            h_out[(size_t)i * HID + j] = hv;
        }
        shh[slot][j] = hv;
        __syncthreads();
        if (act) {
            const float4* hr = (const float4*)(&shh[slot][half * 32]);
            float acc2 = 0.f;
#pragma unroll
            for (int q = 0; q < 8; ++q) {
                float4 r = hr[q];
                acc2 = fmaf(r.x, wm[q * 4 + 0], acc2);
                acc2 = fmaf(r.y, wm[q * 4 + 1], acc2);
                acc2 = fmaf(r.z, wm[q * 4 + 2], acc2);
                acc2 = fmaf(r.w, wm[q * 4 + 3], acc2);
            }
            acc2 += __shfl_xor(acc2, 32);
            if (half == 0) {
                float v = fmaxf(acc2 + bm, 0.f);
                x2_out[(size_t)i * MSG + j2] = v;
                lsum += v; lsq += v * v;
            }
        }
        __syncthreads();
    }
    red[tid] = (half == 0) ? lsum : 0.f; __syncthreads();
    if (tid < 32) atomicAdd(&stats2[tid], red[tid] + red[tid + 64] + red[tid + 128] + red[tid + 192]);
    __syncthreads();
    red[tid] = (half == 0) ? lsq : 0.f; __syncthreads();
    if (tid < 32) atomicAdd(&stats2[32 + tid], red[tid] + red[tid + 64] + red[tid + 128] + red[tid + 192]);
}

// ---------- chain build: head[dst] -> newest edge; pair[e] = {src, next} ----------
__global__ __launch_bounds__(256) void k_build(
    const int* __restrict__ esrc, const int* __restrict__ edst,
    int* __restrict__ head, int2* __restrict__ pair)
{
    const int stride = gridDim.x * blockDim.x;
    for (int e = blockIdx.x * blockDim.x + threadIdx.x; e < EE; e += stride) {
        const int s = esrc[e], d = edst[e];
        const int old = atomicExch(&head[d], e);
        pair[e] = make_int2(s, old);
    }
}

// ---------- K3: chain-walk aggregation: agg[i] = s2*sum x2[src] + deg*t2 ----------
// One 32-lane half-wave per node (lane = channel); two chains interleaved for ILP.
__global__ __launch_bounds__(256) void k_agg_chain(
    const int* __restrict__ head, const int2* __restrict__ pair,
    const float* __restrict__ x2, const float* __restrict__ stats2,
    const float* __restrict__ g_msg, const float* __restrict__ be_msg,
    float* __restrict__ aggout)
{
    const int c = threadIdx.x & 31;
    const int hw = (blockIdx.x * blockDim.x + threadIdx.x) >> 5;
    const int nhw = (gridDim.x * blockDim.x) >> 5;
    const float m = stats2[c] * (1.f / NN);
    const float va = stats2[MSG + c] * (1.f / NN) - m * m;
    const float s = g_msg[c] * rsqrtf(va + EPS);
    const float t = be_msg[c] - m * s;
    for (int i0 = hw; i0 < NN; i0 += 2 * nhw) {
        const int i1 = i0 + nhw;
        int e0 = head[i0];
        int e1 = (i1 < NN) ? head[i1] : -1;
        float S0 = 0.f, S1 = 0.f;
        int d0 = 0, d1 = 0;
        while (e0 >= 0 || e1 >= 0) {
            if (e0 >= 0) {
                const int2 p0 = pair[e0];
                S0 += x2[(size_t)p0.x * MSG + c];
                e0 = p0.y; ++d0;
            }
            if (e1 >= 0) {
                const int2 p1 = pair[e1];
                S1 += x2[(size_t)p1.x * MSG + c];
                e1 = p1.y; ++d1;
            }
        }
        aggout[(size_t)i0 * HID + c] = fmaf(s, S0, (float)d0 * t);
        if (i1 < NN)
            aggout[(size_t)i1 * HID + c] = fmaf(s, S1, (float)d1 * t);
    }
}

// ---------- K4: x3 = relu([agg,h,goal]@W_upd + b); in-place in d_out u-region ----------
__global__ __launch_bounds__(256) void k_upd(
    float* __restrict__ aggx3, const float* __restrict__ h,
    const float* __restrict__ goal, const float* __restrict__ W_upd,
    const float* __restrict__ b_upd, float* __restrict__ stats3)
{
    __shared__ float cat[4][UPD_IN];
    __shared__ float red[256];
    const int tid = threadIdx.x;
    const int j = tid & 63, slot = tid >> 6;
    float w[UPD_IN];
#pragma unroll
    for (int k = 0; k < UPD_IN; ++k) w[k] = W_upd[k * HID + j];
    const float bj = b_upd[j];
    float lsum = 0.f, lsq = 0.f;
    for (int base = blockIdx.x * 4; base < NN; base += gridDim.x * 4) {
        const int i = base + slot;
        const bool act = i < NN;
        if (act) {
            if (j < 32) cat[slot][j] = aggx3[(size_t)i * HID + j];
            cat[slot][32 + j] = h[(size_t)i * HID + j];
            if (j < 16) cat[slot][96 + j] = goal[(size_t)i * GOALD + j];
        }
        __syncthreads();
        if (act) {
            const float4* cr = (const float4*)cat[slot];
            float acc = bj;
#pragma unroll
            for (int q = 0; q < UPD_IN / 4; ++q) {
                float4 r = cr[q];
                acc = fmaf(r.x, w[q * 4 + 0], acc);
                acc = fmaf(r.y, w[q * 4 + 1], acc);
                acc = fmaf(r.z, w[q * 4 + 2], acc);
                acc = fmaf(r.w, w[q * 4 + 3], acc);
            }
            float v = fmaxf(acc, 0.f);
            aggx3[(size_t)i * HID + j] = v;
            lsum += v; lsq += v * v;
        }
        __syncthreads();
    }
    red[tid] = lsum; __syncthreads();
    if (tid < 64) atomicAdd(&stats3[tid], red[tid] + red[tid + 64] + red[tid + 128] + red[tid + 192]);
    __syncthreads();
    red[tid] = lsq; __syncthreads();
    if (tid < 64) atomicAdd(&stats3[64 + tid], red[tid] + red[tid + 64] + red[tid + 128] + red[tid + 192]);
}

// ---------- K5: u = BN3(x3) in-place in d_out; out = u@W_out + b_out ----------
__global__ __launch_bounds__(256) void k_out(
    float* __restrict__ x3u, const float* __restrict__ stats3,
    const float* __restrict__ g_upd, const float* __restrict__ be_upd,
    const float* __restrict__ W_out, const float* __restrict__ b_out,
    float* __restrict__ o_out)
{
    __shared__ float shu[4][HID];
    const int tid = threadIdx.x;
    const int j = tid & 63, slot = tid >> 6;
    const int o = j & 7, part = j >> 3;
    const float m3 = stats3[j] * (1.f / NN);
    const float va3 = stats3[HID + j] * (1.f / NN) - m3 * m3;
    const float s3 = g_upd[j] * rsqrtf(va3 + EPS);
    const float t3 = be_upd[j] - m3 * s3;
    float w[8];
#pragma unroll
    for (int k = 0; k < 8; ++k) w[k] = W_out[(part * 8 + k) * OUTD + o];
    const float bo = b_out[o];
    for (int base = blockIdx.x * 4; base < NN; base += gridDim.x * 4) {
        const int i = base + slot;
        const bool act = i < NN;
        float u = 0.f;
        if (act) {
            u = fmaf(x3u[(size_t)i * HID + j], s3, t3);
            x3u[(size_t)i * HID + j] = u;
        }
        shu[slot][j] = u;
        __syncthreads();
        if (act) {
            const float* ur = &shu[slot][part * 8];
            float acc = 0.f;
#pragma unroll
            for (int k = 0; k < 8; ++k) acc = fmaf(ur[k], w[k], acc);
            acc += __shfl_xor(acc, 8);
            acc += __shfl_xor(acc, 16);
            acc += __shfl_xor(acc, 32);
            if (part == 0) o_out[(size_t)i * OUTD + o] = acc + bo;
        }
        __syncthreads();
    }
}

extern "C" void kernel_launch(void* const* d_in, const int* in_sizes, int n_in,
                              void* d_out, int out_size, void* d_ws, size_t ws_size,
                              hipStream_t stream)
{
    (void)in_sizes; (void)n_in; (void)out_size;
    const float* nodes  = (const float*)d_in[0];
    const float* goal   = (const float*)d_in[1];
    const int*   esrc   = (const int*)d_in[2];
    const int*   edst   = (const int*)d_in[3];
    const float* W_in   = (const float*)d_in[6];
    const float* b_in   = (const float*)d_in[7];
    const float* g_in   = (const float*)d_in[8];
    const float* be_in  = (const float*)d_in[9];
    const float* W_msg  = (const float*)d_in[10];
    const float* b_msg  = (const float*)d_in[11];
    const float* g_msg  = (const float*)d_in[12];
    const float* be_msg = (const float*)d_in[13];
    const float* W_upd  = (const float*)d_in[14];
    const float* b_upd  = (const float*)d_in[15];
    const float* g_upd  = (const float*)d_in[16];
    const float* be_upd = (const float*)d_in[17];
    const float* W_out  = (const float*)d_in[18];
    const float* b_out  = (const float*)d_in[19];

    // ws: stats(320 f32) | h(N*64 f32) | x2(N*32 f32) | head(N int) | pair(E int2)
    const size_t need = (320 + (size_t)NN * 96) * sizeof(float)
                      + (size_t)NN * sizeof(int) + (size_t)EE * sizeof(int2);
    if (ws_size < need) return;  // fail soft instead of OOB-faulting

    float* st = (float*)d_ws;
    float* stats1 = st;        // 128
    float* stats2 = st + 128;  // 64
    float* stats3 = st + 192;  // 128
    float* h  = st + 320;                  // N*64
    float* x2 = h + (size_t)NN * 64;       // N*32
    int*  head = (int*)(x2 + (size_t)NN * 32);   // N
    int2* pair = (int2*)(head + NN);             // E (8B-aligned)

    float* u_out = (float*)d_out;                    // N*64 (agg cols 0..31 -> x3 -> u)
    float* o_out = (float*)d_out + (size_t)NN * HID; // N*8

    hipMemsetAsync(st, 0, 320 * sizeof(float), stream);
    hipMemsetAsync(head, 0xFF, NN * sizeof(int), stream);  // head = -1

    k_build<<<2048, 256, 0, stream>>>(esrc, edst, head, pair);
    k_in_stats<<<1024, 256, 0, stream>>>(nodes, W_in, b_in, stats1);
    k_h_msg<<<1024, 256, 0, stream>>>(nodes, W_in, b_in, stats1, g_in, be_in,
                                      W_msg, b_msg, h, x2, stats2);
    k_agg_chain<<<2048, 256, 0, stream>>>(head, pair, x2, stats2, g_msg, be_msg, u_out);
    k_upd<<<1024, 256, 0, stream>>>(u_out, h, goal, W_upd, b_upd, stats3);
    k_out<<<1024, 256, 0, stream>>>(u_out, stats3, g_upd, be_upd, W_out, b_out, o_out);
}

// Round 11
// 445.238 us; speedup vs baseline: 1.7915x; 1.0797x over previous
//
#include <hip/hip_runtime.h>
#include <stdint.h>

#define NN 100000
#define EE 1600000
#define FEAT 32
#define HID 64
#define MSG 32
#define GOALD 16
#define OUTD 8
#define UPD_IN 112
#define EPS 1e-5f

__device__ inline unsigned bf16rne(float f) {
    unsigned u = __float_as_uint(f);
    return (u + 0x7FFF + ((u >> 16) & 1)) >> 16;
}

// ---------- K_pre: chain build (blocks 0..2047) || column stats of x1 (blocks 2048..3071) ----------
__global__ __launch_bounds__(256) void k_pre(
    const int* __restrict__ esrc, const int* __restrict__ edst,
    int* __restrict__ head, int2* __restrict__ pair,
    const float* __restrict__ nodes, const float* __restrict__ W_in,
    const float* __restrict__ b_in, float* __restrict__ stats1)
{
    if (blockIdx.x < 2048) {
        // chain build: head[dst] -> newest edge; pair[e] = {src, next}
        const int stride = 2048 * 256;
        for (int e = blockIdx.x * 256 + threadIdx.x; e < EE; e += stride) {
            const int s = esrc[e], d = edst[e];
            const int old = atomicExch(&head[d], e);
            pair[e] = make_int2(s, old);
        }
    } else {
        __shared__ float red[256];
        const int bid = blockIdx.x - 2048;  // 0..1023
        const int tid = threadIdx.x;
        const int j = tid & 63, slot = tid >> 6;
        float w[FEAT];
#pragma unroll
        for (int k = 0; k < FEAT; ++k) w[k] = W_in[k * HID + j];
        const float bj = b_in[j];
        float lsum = 0.f, lsq = 0.f;
        for (int i = bid * 4 + slot; i < NN; i += 1024 * 4) {
            const float4* row = (const float4*)(nodes + (size_t)i * FEAT);
            float acc = bj;
#pragma unroll
            for (int q = 0; q < FEAT / 4; ++q) {
                float4 r = row[q];
                acc = fmaf(r.x, w[q * 4 + 0], acc);
                acc = fmaf(r.y, w[q * 4 + 1], acc);
                acc = fmaf(r.z, w[q * 4 + 2], acc);
                acc = fmaf(r.w, w[q * 4 + 3], acc);
            }
            float v = fmaxf(acc, 0.f);
            lsum += v; lsq += v * v;
        }
        red[tid] = lsum; __syncthreads();
        if (tid < 64) atomicAdd(&stats1[tid], red[tid] + red[tid + 64] + red[tid + 128] + red[tid + 192]);
        __syncthreads();
        red[tid] = lsq; __syncthreads();
        if (tid < 64) atomicAdd(&stats1[64 + tid], red[tid] + red[tid + 64] + red[tid + 128] + red[tid + 192]);
    }
}

// ---------- K2: h = BN1(relu(nodes@W_in+b)) stored f32; x2 stored packed bf16x2; stats2 ----------
__global__ __launch_bounds__(256) void k_h_msg(
    const float* __restrict__ nodes, const float* __restrict__ W_in,
    const float* __restrict__ b_in, const float* __restrict__ stats1,
    const float* __restrict__ g_in, const float* __restrict__ be_in,
    const float* __restrict__ W_msg, const float* __restrict__ b_msg,
    float* __restrict__ h_out, unsigned* __restrict__ x2b_out,
    float* __restrict__ stats2)
{
    __shared__ float shh[4][HID];
    __shared__ float red[256];
    const int tid = threadIdx.x;
    const int j = tid & 63, slot = tid >> 6;
    const int j2 = j & 31, half = j >> 5;
    float w[FEAT];
#pragma unroll
    for (int k = 0; k < FEAT; ++k) w[k] = W_in[k * HID + j];
    float wm[32];
#pragma unroll
    for (int k = 0; k < 32; ++k) wm[k] = W_msg[(half * 32 + k) * MSG + j2];
    const float bj = b_in[j];
    const float m1 = stats1[j] * (1.f / NN);
    const float va1 = stats1[HID + j] * (1.f / NN) - m1 * m1;
    const float s1 = g_in[j] * rsqrtf(va1 + EPS);
    const float t1 = be_in[j] - m1 * s1;
    const float bm = b_msg[j2];
    float lsum = 0.f, lsq = 0.f;
    for (int base = blockIdx.x * 4; base < NN; base += gridDim.x * 4) {
        const int i = base + slot;
        const bool act = i < NN;
        float hv = 0.f;
        if (act) {
            const float4* row = (const float4*)(nodes + (size_t)i * FEAT);
            float acc = bj;
#pragma unroll
            for (int q = 0; q < FEAT / 4; ++q) {
                float4 r = row[q];
                acc = fmaf(r.x, w[q * 4 + 0], acc);
                acc = fmaf(r.y, w[q * 4 + 1], acc);
                acc = fmaf(r.z, w[q * 4 + 2], acc);
                acc = fmaf(r.w, w[q * 4 + 3], acc);
            }
            hv = fmaf(fmaxf(acc, 0.f), s1, t1);
            h_out[(size_t)i * HID + j] = hv;
        }
        shh[slot][j] = hv;
        __syncthreads();
        float v = 0.f;
        if (act) {
            const float4* hr = (const float4*)(&shh[slot][half * 32]);
            float acc2 = 0.f;
#pragma unroll
            for (int q = 0; q < 8; ++q) {
                float4 r = hr[q];
                acc2 = fmaf(r.x, wm[q * 4 + 0], acc2);
                acc2 = fmaf(r.y, wm[q * 4 + 1], acc2);
                acc2 = fmaf(r.z, wm[q * 4 + 2], acc2);
                acc2 = fmaf(r.w, wm[q * 4 + 3], acc2);
            }
            acc2 += __shfl_xor(acc2, 32);   // both halves now hold the full dot
            v = fmaxf(acc2 + bm, 0.f);
            if (half == 0) { lsum += v; lsq += v * v; }
        }
        // pack channel pair (2k, 2k+1) into u32; lane j2=2k writes
        const float vn = __shfl_xor(v, 1);
        if (act && half == 0 && (j2 & 1) == 0) {
            const unsigned pk = bf16rne(v) | (bf16rne(vn) << 16);
            x2b_out[(size_t)i * (MSG / 2) + (j2 >> 1)] = pk;
        }
        __syncthreads();
    }
    red[tid] = (half == 0) ? lsum : 0.f; __syncthreads();
    if (tid < 32) atomicAdd(&stats2[tid], red[tid] + red[tid + 64] + red[tid + 128] + red[tid + 192]);
    __syncthreads();
    red[tid] = (half == 0) ? lsq : 0.f; __syncthreads();
    if (tid < 32) atomicAdd(&stats2[32 + tid], red[tid] + red[tid + 64] + red[tid + 128] + red[tid + 192]);
}

// ---------- K3: chain-walk aggregation over bf16 x2 ----------
// 16-lane group per node (lane = channel pair); 4 groups/wave; 2 chains interleaved.
__global__ __launch_bounds__(256) void k_agg_chain(
    const int* __restrict__ head, const int2* __restrict__ pair,
    const unsigned* __restrict__ x2b, const float* __restrict__ stats2,
    const float* __restrict__ g_msg, const float* __restrict__ be_msg,
    float* __restrict__ aggout)
{
    const int l = threadIdx.x & 15;          // channel pair index
    const int c0 = l * 2, c1 = c0 + 1;
    const int grp = (blockIdx.x * blockDim.x + threadIdx.x) >> 4;
    const int ngrp = (gridDim.x * blockDim.x) >> 4;
    const float m0 = stats2[c0] * (1.f / NN);
    const float m1 = stats2[c1] * (1.f / NN);
    const float va0 = stats2[MSG + c0] * (1.f / NN) - m0 * m0;
    const float va1 = stats2[MSG + c1] * (1.f / NN) - m1 * m1;
    const float s0 = g_msg[c0] * rsqrtf(va0 + EPS);
    const float s1 = g_msg[c1] * rsqrtf(va1 + EPS);
    const float t0 = be_msg[c0] - m0 * s0;
    const float t1 = be_msg[c1] - m1 * s1;
    for (int i0 = grp; i0 < NN; i0 += 2 * ngrp) {
        const int i1 = i0 + ngrp;
        int e0 = head[i0];
        int e1 = (i1 < NN) ? head[i1] : -1;
        float A0 = 0.f, B0 = 0.f, A1 = 0.f, B1 = 0.f;
        int d0 = 0, d1 = 0;
        while (e0 >= 0 || e1 >= 0) {
            if (e0 >= 0) {
                const int2 p = pair[e0];
                const unsigned pk = x2b[(size_t)p.x * (MSG / 2) + l];
                A0 += __uint_as_float(pk << 16);
                B0 += __uint_as_float(pk & 0xFFFF0000u);
                e0 = p.y; ++d0;
            }
            if (e1 >= 0) {
                const int2 p = pair[e1];
                const unsigned pk = x2b[(size_t)p.x * (MSG / 2) + l];
                A1 += __uint_as_float(pk << 16);
                B1 += __uint_as_float(pk & 0xFFFF0000u);
                e1 = p.y; ++d1;
            }
        }
        float2 o;
        o.x = fmaf(s0, A0, (float)d0 * t0);
        o.y = fmaf(s1, B0, (float)d0 * t1);
        ((float2*)(aggout + (size_t)i0 * HID))[l] = o;
        if (i1 < NN) {
            o.x = fmaf(s0, A1, (float)d1 * t0);
            o.y = fmaf(s1, B1, (float)d1 * t1);
            ((float2*)(aggout + (size_t)i1 * HID))[l] = o;
        }
    }
}

// ---------- K4: x3 = relu([agg,h,goal]@W_upd + b); in-place in d_out u-region ----------
__global__ __launch_bounds__(256) void k_upd(
    float* __restrict__ aggx3, const float* __restrict__ h,
    const float* __restrict__ goal, const float* __restrict__ W_upd,
    const float* __restrict__ b_upd, float* __restrict__ stats3)
{
    __shared__ float cat[4][UPD_IN];
    __shared__ float red[256];
    const int tid = threadIdx.x;
    const int j = tid & 63, slot = tid >> 6;
    float w[UPD_IN];
#pragma unroll
    for (int k = 0; k < UPD_IN; ++k) w[k] = W_upd[k * HID + j];
    const float bj = b_upd[j];
    float lsum = 0.f, lsq = 0.f;
    for (int base = blockIdx.x * 4; base < NN; base += gridDim.x * 4) {
        const int i = base + slot;
        const bool act = i < NN;
        if (act) {
            if (j < 32) cat[slot][j] = aggx3[(size_t)i * HID + j];
            cat[slot][32 + j] = h[(size_t)i * HID + j];
            if (j < 16) cat[slot][96 + j] = goal[(size_t)i * GOALD + j];
        }
        __syncthreads();
        if (act) {
            const float4* cr = (const float4*)cat[slot];
            float acc = bj;
#pragma unroll
            for (int q = 0; q < UPD_IN / 4; ++q) {
                float4 r = cr[q];
                acc = fmaf(r.x, w[q * 4 + 0], acc);
                acc = fmaf(r.y, w[q * 4 + 1], acc);
                acc = fmaf(r.z, w[q * 4 + 2], acc);
                acc = fmaf(r.w, w[q * 4 + 3], acc);
            }
            float v = fmaxf(acc, 0.f);
            aggx3[(size_t)i * HID + j] = v;
            lsum += v; lsq += v * v;
        }
        __syncthreads();
    }
    red[tid] = lsum; __syncthreads();
    if (tid < 64) atomicAdd(&stats3[tid], red[tid] + red[tid + 64] + red[tid + 128] + red[tid + 192]);
    __syncthreads();
    red[tid] = lsq; __syncthreads();
    if (tid < 64) atomicAdd(&stats3[64 + tid], red[tid] + red[tid + 64] + red[tid + 128] + red[tid + 192]);
}

// ---------- K5: u = BN3(x3) in-place in d_out; out = u@W_out + b_out ----------
__global__ __launch_bounds__(256) void k_out(
    float* __restrict__ x3u, const float* __restrict__ stats3,
    const float* __restrict__ g_upd, const float* __restrict__ be_upd,
    const float* __restrict__ W_out, const float* __restrict__ b_out,
    float* __restrict__ o_out)
{
    __shared__ float shu[4][HID];
    const int tid = threadIdx.x;
    const int j = tid & 63, slot = tid >> 6;
    const int o = j & 7, part = j >> 3;
    const float m3 = stats3[j] * (1.f / NN);
    const float va3 = stats3[HID + j] * (1.f / NN) - m3 * m3;
    const float s3 = g_upd[j] * rsqrtf(va3 + EPS);
    const float t3 = be_upd[j] - m3 * s3;
    float w[8];
#pragma unroll
    for (int k = 0; k < 8; ++k) w[k] = W_out[(part * 8 + k) * OUTD + o];
    const float bo = b_out[o];
    for (int base = blockIdx.x * 4; base < NN; base += gridDim.x * 4) {
        const int i = base + slot;
        const bool act = i < NN;
        float u = 0.f;
        if (act) {
            u = fmaf(x3u[(size_t)i * HID + j], s3, t3);
            x3u[(size_t)i * HID + j] = u;
        }
        shu[slot][j] = u;
        __syncthreads();
        if (act) {
            const float* ur = &shu[slot][part * 8];
            float acc = 0.f;
#pragma unroll
            for (int k = 0; k < 8; ++k) acc = fmaf(ur[k], w[k], acc);
            acc += __shfl_xor(acc, 8);
            acc += __shfl_xor(acc, 16);
            acc += __shfl_xor(acc, 32);
            if (part == 0) o_out[(size_t)i * OUTD + o] = acc + bo;
        }
        __syncthreads();
    }
}

extern "C" void kernel_launch(void* const* d_in, const int* in_sizes, int n_in,
                              void* d_out, int out_size, void* d_ws, size_t ws_size,
                              hipStream_t stream)
{
    (void)in_sizes; (void)n_in; (void)out_size;
    const float* nodes  = (const float*)d_in[0];
    const float* goal   = (const float*)d_in[1];
    const int*   esrc   = (const int*)d_in[2];
    const int*   edst   = (const int*)d_in[3];
    const float* W_in   = (const float*)d_in[6];
    const float* b_in   = (const float*)d_in[7];
    const float* g_in   = (const float*)d_in[8];
    const float* be_in  = (const float*)d_in[9];
    const float* W_msg  = (const float*)d_in[10];
    const float* b_msg  = (const float*)d_in[11];
    const float* g_msg  = (const float*)d_in[12];
    const float* be_msg = (const float*)d_in[13];
    const float* W_upd  = (const float*)d_in[14];
    const float* b_upd  = (const float*)d_in[15];
    const float* g_upd  = (const float*)d_in[16];
    const float* be_upd = (const float*)d_in[17];
    const float* W_out  = (const float*)d_in[18];
    const float* b_out  = (const float*)d_in[19];

    // ws: stats(320 f32) | h(N*64 f32) | x2b(N*16 u32) | head(N int) | pair(E int2)
    const size_t need = (320 + (size_t)NN * 80) * sizeof(float)
                      + (size_t)NN * sizeof(int) + (size_t)EE * sizeof(int2);
    if (ws_size < need) return;  // fail soft instead of OOB-faulting

    float* st = (float*)d_ws;
    float* stats1 = st;        // 128
    float* stats2 = st + 128;  // 64
    float* stats3 = st + 192;  // 128
    float* h  = st + 320;                      // N*64 f32
    unsigned* x2b = (unsigned*)(h + (size_t)NN * 64);  // N*16 u32
    int*  head = (int*)(x2b + (size_t)NN * 16);        // N
    int2* pair = (int2*)(head + NN);                   // E (8B-aligned)

    float* u_out = (float*)d_out;                    // N*64 (agg cols 0..31 -> x3 -> u)
    float* o_out = (float*)d_out + (size_t)NN * HID; // N*8

    hipMemsetAsync(st, 0, 320 * sizeof(float), stream);
    hipMemsetAsync(head, 0xFF, NN * sizeof(int), stream);  // head = -1

    k_pre<<<3072, 256, 0, stream>>>(esrc, edst, head, pair, nodes, W_in, b_in, stats1);
    k_h_msg<<<1024, 256, 0, stream>>>(nodes, W_in, b_in, stats1, g_in, be_in,
                                      W_msg, b_msg, h, x2b, stats2);
    k_agg_chain<<<2048, 256, 0, stream>>>(head, pair, x2b, stats2, g_msg, be_msg, u_out);
    k_upd<<<1024, 256, 0, stream>>>(u_out, h, goal, W_upd, b_upd, stats3);
    k_out<<<1024, 256, 0, stream>>>(u_out, stats3, g_upd, be_upd, W_out, b_out, o_out);
}